// Round 23
// baseline (175.440 us; speedup 1.0000x reference)
//
#include <hip/hip_runtime.h>
#include <hip/hip_fp16.h>

#define N_NODES 100000
#define N_EDGES 1600000
#define IN_DIM  128
#define OUT_DIM 64
#define HEADS   4
#define SLOPE   0.2f
#define CLIP_LO 0.005f
#define CLIP_HI 10.0f
#define NRANGE 250
#define RANGE_SZ 400         // N_NODES / NRANGE (exact)
#define EDGES_PER_BLK 2048   // 8 edges/thread * 256
#define CHUNKS 782           // ceil(N_EDGES / EDGES_PER_BLK)
#define GEMM_BLOCKS 1563     // ceil(N_NODES/64)
#define S_BLOCKS 391         // ceil(N_NODES/256)
#define BUCKET 48            // fixed per-dst CSR capacity
#define BIN_CAP 32           // per-(range,chunk) LDS bin capacity (mean 8.2)
#define CAPR 8192            // dense per-range list capacity (mean 6400, +22 sigma)

typedef short bf16x8 __attribute__((ext_vector_type(8)));
typedef float f32x4  __attribute__((ext_vector_type(4)));

__device__ __forceinline__ short f2bf(float x) {
    union { float f; unsigned u; } v; v.f = x;
    unsigned r = (v.u + 0x7FFF + ((v.u >> 16) & 1)) >> 16;   // RNE
    return (short)r;
}
__device__ __forceinline__ unsigned short f2hbits(float x) {
    union { __half h; unsigned short u; } c; c.h = __float2half(x); return c.u;
}
__device__ __forceinline__ float hbits2f(unsigned short b) {
    union { __half h; unsigned short u; } c; c.u = b; return __half2float(c.h);
}

// ---------------------------------------------------------------------------
// prep: WcatT[n][i]=bf16(W[k][i][j]) (n=k*64+j) and Wa[k][half][i]
// ---------------------------------------------------------------------------
__global__ __launch_bounds__(256) void prep_kernel(const float* __restrict__ W,
                                                   const float* __restrict__ a,
                                                   short* __restrict__ WcatT,
                                                   float* __restrict__ Wa) {
    int idx = blockIdx.x * 256 + threadIdx.x;
    if (idx < 256 * 128) {
        int n = idx >> 7, i = idx & 127;
        int k = n >> 6, j = n & 63;
        WcatT[idx] = f2bf(W[((size_t)k * IN_DIM + i) * OUT_DIM + j]);
    } else if (idx < 256 * 128 + 1024) {
        int o = idx - 256 * 128;
        int k = o >> 8, half = (o >> 7) & 1, i = o & 127;
        const float* wrow = W + ((size_t)k * IN_DIM + i) * OUT_DIM;
        const float* av   = a + k * 2 * OUT_DIM + half * OUT_DIM;
        float acc = 0.f;
#pragma unroll 8
        for (int j = 0; j < OUT_DIM; ++j) acc += wrow[j] * av[j];
        Wa[o] = acc;
    }
}

// ---------------------------------------------------------------------------
// s_bin: blocks [0,S_BLOCKS) = exact-f32 scores; blocks [S_BLOCKS,+CHUNKS) =
// binning into 250 ranges, flushed to DENSE per-range lists (one global
// atomic per (range,chunk) reserves the slice).
// ---------------------------------------------------------------------------
__global__ __launch_bounds__(256) void s_bin(const float* __restrict__ h,
                                             const float* __restrict__ Wa,
                                             const int* __restrict__ edges,
                                             unsigned* __restrict__ dense,
                                             int* __restrict__ rangeCnt,
                                             float* __restrict__ sS,
                                             float* __restrict__ sD) {
    __shared__ __align__(16) char smem[35072];   // 1024 cnt + 32000 bents + 1024 pos
    if (blockIdx.x >= S_BLOCKS) {
        int* bcnt = (int*)smem;                        // 250 ints (1024B pad)
        unsigned* bents = (unsigned*)(smem + 1024);    // [250][32] = 32000B
        int* posL = (int*)(smem + 33024);              // 250 ints
        const int c = blockIdx.x - S_BLOCKS;
        const int base = c * EDGES_PER_BLK + threadIdx.x * 8;
        for (int t = threadIdx.x; t < NRANGE; t += 256) bcnt[t] = 0;
        __syncthreads();
        if (base < N_EDGES) {
            int4 s0 = *(const int4*)(edges + base);
            int4 s1 = *(const int4*)(edges + base + 4);
            int4 d0 = *(const int4*)(edges + N_EDGES + base);
            int4 d1 = *(const int4*)(edges + N_EDGES + base + 4);
            int ss[8] = {s0.x, s0.y, s0.z, s0.w, s1.x, s1.y, s1.z, s1.w};
            int dd[8] = {d0.x, d0.y, d0.z, d0.w, d1.x, d1.y, d1.z, d1.w};
#pragma unroll
            for (int u = 0; u < 8; ++u) {
                unsigned d = (unsigned)dd[u];
                unsigned r = d / (unsigned)RANGE_SZ;
                int pos = atomicAdd(&bcnt[r], 1);
                if (pos < BIN_CAP)
                    bents[r * BIN_CAP + pos] = ((unsigned)ss[u] << 9) | (d - r * RANGE_SZ);
            }
        }
        __syncthreads();
        if (threadIdx.x < NRANGE) {
            int n = bcnt[threadIdx.x]; if (n > BIN_CAP) n = BIN_CAP;
            bcnt[threadIdx.x] = n;
            posL[threadIdx.x] = atomicAdd(&rangeCnt[threadIdx.x], n);
        }
        __syncthreads();
        for (int idx = threadIdx.x; idx < NRANGE * BIN_CAP; idx += 256) {
            int r = idx >> 5, i = idx & 31;
            if (i < bcnt[r]) {
                int p = posL[r] + i;
                if (p < CAPR) dense[(size_t)r * CAPR + p] = bents[r * BIN_CAP + i];
            }
        }
        return;
    }

    float* wa_s = (float*)smem;
    for (int t = threadIdx.x; t < HEADS * 2 * IN_DIM; t += 256) wa_s[t] = Wa[t];
    __syncthreads();
    int n = blockIdx.x * 256 + threadIdx.x;
    if (n >= N_NODES) return;
    const float4* hv = (const float4*)(h + (size_t)n * IN_DIM);
    const float4* wv = (const float4*)wa_s;
    float acc[8] = {0.f,0.f,0.f,0.f,0.f,0.f,0.f,0.f};
    for (int i4 = 0; i4 < IN_DIM / 4; ++i4) {
        float4 hx = hv[i4];
#pragma unroll
        for (int k2 = 0; k2 < 8; ++k2) {
            float4 w = wv[k2 * (IN_DIM / 4) + i4];
            acc[k2] += hx.x * w.x + hx.y * w.y + hx.z * w.z + hx.w * w.w;
        }
    }
    *(float4*)(sS + (size_t)n * 4) = make_float4(acc[0], acc[2], acc[4], acc[6]);
    *(float4*)(sD + (size_t)n * 4) = make_float4(acc[1], acc[3], acc[5], acc[7]);
}

// ---------------------------------------------------------------------------
__device__ __forceinline__ float edge_e(float x) {
    x = x > 0.f ? x : SLOPE * x;
    float ev = __expf(x);
    return fminf(fmaxf(ev, CLIP_LO), CLIP_HI);
}

// ---------------------------------------------------------------------------
// gemm_scatter: blocks [0,NRANGE) = range-owned scatter over DENSE lists
// (uint4 reads, 4 edges/thread/iter, LDS counters, zero global atomics);
// blocks [NRANGE,+GEMM_BLOCKS) = MFMA GEMM + int8 epilogue.
// ---------------------------------------------------------------------------
__global__ __launch_bounds__(256) void gemm_scatter(const float* __restrict__ h,
                                                    const short* __restrict__ WcatT,
                                                    const unsigned* __restrict__ dense,
                                                    const int* __restrict__ rangeCnt,
                                                    const float4* __restrict__ sArrS,
                                                    const float4* __restrict__ sArrD,
                                                    int* __restrict__ cnt,
                                                    uint4* __restrict__ csr,
                                                    unsigned char* __restrict__ hw8,
                                                    float* __restrict__ scaleArr) {
    __shared__ __align__(16) char smem[64 * 136 * 2];   // 17408B union

    if (blockIdx.x < NRANGE) {
        // ---- range-owned scatter over dense list ----
        int*    cntL = (int*)smem;               // 1600B
        float4* dvL  = (float4*)(smem + 1664);   // 6400B
        const int r = blockIdx.x;
        for (int t = threadIdx.x; t < RANGE_SZ; t += 256) {
            cntL[t] = 0;
            dvL[t]  = sArrD[r * RANGE_SZ + t];
        }
        __syncthreads();

        int n = rangeCnt[r]; if (n > CAPR) n = CAPR;
        const unsigned* dl = dense + (size_t)r * CAPR;
        for (int i0 = threadIdx.x * 4; i0 < n; i0 += 1024) {
            // aligned uint4 read of 4 entries (dense base 16B-aligned)
            uint4 e4 = *(const uint4*)(dl + i0);
            unsigned ent[4] = {e4.x, e4.y, e4.z, e4.w};
            int nv = n - i0; if (nv > 4) nv = 4;
            float4 sv[4], dv[4];
#pragma unroll
            for (int u = 0; u < 4; ++u) {
                if (u < nv) {
                    sv[u] = sArrS[ent[u] >> 9];
                    dv[u] = dvL[ent[u] & 511];
                }
            }
#pragma unroll
            for (int u = 0; u < 4; ++u) {
                if (u < nv) {
                    int s  = ent[u] >> 9;
                    int dloc = ent[u] & 511;
                    uint4 rec;
                    rec.x = (unsigned)s;
                    rec.y = f2hbits(edge_e(sv[u].x + dv[u].x)) | ((unsigned)f2hbits(edge_e(sv[u].y + dv[u].y)) << 16);
                    rec.z = f2hbits(edge_e(sv[u].z + dv[u].z)) | ((unsigned)f2hbits(edge_e(sv[u].w + dv[u].w)) << 16);
                    rec.w = 0;
                    int pos = atomicAdd(&cntL[dloc], 1);   // LDS atomic
                    if (pos < BUCKET)
                        csr[(size_t)(r * RANGE_SZ + dloc) * BUCKET + pos] = rec;
                }
            }
        }
        __syncthreads();
        for (int t = threadIdx.x; t < RANGE_SZ; t += 256) {
            int v = cntL[t];
            cnt[r * RANGE_SZ + t] = v > BUCKET ? BUCKET : v;
        }
        return;
    }

    // ---- GEMM + int8 epilogue (R19-proven) ----
    short (*As)[136] = (short(*)[136])smem;
    const int row0 = (blockIdx.x - NRANGE) * 64;
    const int tid  = threadIdx.x;

#pragma unroll
    for (int u = 0; u < 4; ++u) {
        int e = (tid + u * 256) * 8;
        int r = e >> 7, c = e & 127;
        int grow = row0 + r; if (grow >= N_NODES) grow = N_NODES - 1;
        const float* hp = h + (size_t)grow * IN_DIM + c;
        float4 v0 = *(const float4*)hp;
        float4 v1 = *(const float4*)(hp + 4);
        bf16x8 b;
        b[0]=f2bf(v0.x); b[1]=f2bf(v0.y); b[2]=f2bf(v0.z); b[3]=f2bf(v0.w);
        b[4]=f2bf(v1.x); b[5]=f2bf(v1.y); b[6]=f2bf(v1.z); b[7]=f2bf(v1.w);
        *(bf16x8*)&As[r][c] = b;
    }
    __syncthreads();

    const int wv = tid >> 6, lane = tid & 63;
    const int lrow = lane & 15;
    const int lk   = (lane >> 4) * 8;

    bf16x8 bfr[4][4];
#pragma unroll
    for (int nt = 0; nt < 4; ++nt)
#pragma unroll
        for (int ks = 0; ks < 4; ++ks)
            bfr[nt][ks] = *(const bf16x8*)(WcatT + (size_t)(wv * 64 + nt * 16 + lrow) * 128 + ks * 32 + lk);

    f32x4 acc[4][4] = {};
#pragma unroll
    for (int ks = 0; ks < 4; ++ks) {
        bf16x8 afr[4];
#pragma unroll
        for (int mt = 0; mt < 4; ++mt)
            afr[mt] = *(const bf16x8*)&As[mt * 16 + lrow][ks * 32 + lk];
#pragma unroll
        for (int mt = 0; mt < 4; ++mt)
#pragma unroll
            for (int nt = 0; nt < 4; ++nt)
                acc[mt][nt] = __builtin_amdgcn_mfma_f32_16x16x32_bf16(afr[mt], bfr[nt][ks], acc[mt][nt], 0, 0, 0);
    }

    const int rgrp = lane >> 4;
#pragma unroll
    for (int mt = 0; mt < 4; ++mt)
#pragma unroll
        for (int reg = 0; reg < 4; ++reg) {
            int g = row0 + mt * 16 + rgrp * 4 + reg;
            float m = fmaxf(fmaxf(fabsf(acc[mt][0][reg]), fabsf(acc[mt][1][reg])),
                            fmaxf(fabsf(acc[mt][2][reg]), fabsf(acc[mt][3][reg])));
#pragma unroll
            for (int off = 1; off < 16; off <<= 1)
                m = fmaxf(m, __shfl_xor(m, off));
            float scale = m > 0.f ? m * (1.f / 127.f) : 1.f;
            float inv   = m > 0.f ? 127.f / m : 0.f;
            uchar4 q;
            q.x = (unsigned char)(int)rintf(acc[mt][0][reg] * inv + 128.f);
            q.y = (unsigned char)(int)rintf(acc[mt][1][reg] * inv + 128.f);
            q.z = (unsigned char)(int)rintf(acc[mt][2][reg] * inv + 128.f);
            q.w = (unsigned char)(int)rintf(acc[mt][3][reg] * inv + 128.f);
            if (g < N_NODES) {
                *(uchar4*)(hw8 + (size_t)g * 256 + wv * 64 + lrow * 4) = q;
                if (lrow == 0) scaleArr[(size_t)g * 4 + wv] = scale;
            }
        }
}

// ---------------------------------------------------------------------------
__device__ __forceinline__ float pickw(const uint4& r, int kh) {
    unsigned wp = (kh & 2) ? r.z : r.y;
    return hbits2f((unsigned short)((kh & 1) ? (wp >> 16) : (wp & 0xffff)));
}
__device__ __forceinline__ void qacc(float4& lo, float4& hi, uint2 g, float ws) {
    float wb = -128.f * ws;
    unsigned x = g.x, y = g.y;
    lo.x += fmaf((float)( x        & 255u), ws, wb);
    lo.y += fmaf((float)((x >> 8 ) & 255u), ws, wb);
    lo.z += fmaf((float)((x >> 16) & 255u), ws, wb);
    lo.w += fmaf((float)( x >> 24        ), ws, wb);
    hi.x += fmaf((float)( y        & 255u), ws, wb);
    hi.y += fmaf((float)((y >> 8 ) & 255u), ws, wb);
    hi.z += fmaf((float)((y >> 16) & 255u), ws, wb);
    hi.w += fmaf((float)( y >> 24        ), ws, wb);
}

// msg_csr over int8 hw (R19-proven)
__global__ __launch_bounds__(256) void msg_csr(const int* __restrict__ cnt,
                                               const uint4* __restrict__ csr,
                                               const unsigned char* __restrict__ hw8,
                                               const float* __restrict__ scaleArr,
                                               float* __restrict__ out) {
    int wid  = (blockIdx.x * 256 + threadIdx.x) >> 6;
    int lane = threadIdx.x & 63;
    if (wid >= N_NODES) return;
    const size_t start = (size_t)wid * BUCKET;
    int dg = cnt[wid];
    if (dg > BUCKET) dg = BUCKET;

    const int es = lane >> 5;
    const int kh = (lane & 31) >> 3;
    const int cg = lane & 7;
    const size_t coff = (size_t)((kh << 6) + (cg << 3));

    float4 alo = make_float4(0.f,0.f,0.f,0.f), ahi = make_float4(0.f,0.f,0.f,0.f);
    float den = 0.f;
    int i = 0;
    for (; i + 8 <= dg; i += 8) {
        uint4 r0 = csr[start + i     + es];
        uint4 r1 = csr[start + i + 2 + es];
        uint4 r2 = csr[start + i + 4 + es];
        uint4 r3 = csr[start + i + 6 + es];
        uint2 g0 = *(const uint2*)(hw8 + (((size_t)r0.x) << 8) + coff);
        uint2 g1 = *(const uint2*)(hw8 + (((size_t)r1.x) << 8) + coff);
        uint2 g2 = *(const uint2*)(hw8 + (((size_t)r2.x) << 8) + coff);
        uint2 g3 = *(const uint2*)(hw8 + (((size_t)r3.x) << 8) + coff);
        float sc0 = scaleArr[(size_t)r0.x * 4 + kh];
        float sc1 = scaleArr[(size_t)r1.x * 4 + kh];
        float sc2 = scaleArr[(size_t)r2.x * 4 + kh];
        float sc3 = scaleArr[(size_t)r3.x * 4 + kh];
        float w0 = pickw(r0, kh);
        float w1 = pickw(r1, kh);
        float w2 = pickw(r2, kh);
        float w3 = pickw(r3, kh);
        den += (w0 + w1) + (w2 + w3);
        qacc(alo, ahi, g0, w0 * sc0);
        qacc(alo, ahi, g1, w1 * sc1);
        qacc(alo, ahi, g2, w2 * sc2);
        qacc(alo, ahi, g3, w3 * sc3);
    }
    for (; i + 4 <= dg; i += 4) {
        uint4 r0 = csr[start + i     + es];
        uint4 r1 = csr[start + i + 2 + es];
        uint2 g0 = *(const uint2*)(hw8 + (((size_t)r0.x) << 8) + coff);
        uint2 g1 = *(const uint2*)(hw8 + (((size_t)r1.x) << 8) + coff);
        float sc0 = scaleArr[(size_t)r0.x * 4 + kh];
        float sc1 = scaleArr[(size_t)r1.x * 4 + kh];
        float w0 = pickw(r0, kh);
        float w1 = pickw(r1, kh);
        den += w0 + w1;
        qacc(alo, ahi, g0, w0 * sc0);
        qacc(alo, ahi, g1, w1 * sc1);
    }
    for (; i < dg; i += 2) {
        int idx = i + es;
        bool valid = idx < dg;
        if (idx >= dg) idx = dg - 1;
        uint4 r = csr[start + idx];
        uint2 g = *(const uint2*)(hw8 + (((size_t)r.x) << 8) + coff);
        float sc = scaleArr[(size_t)r.x * 4 + kh];
        float w = valid ? pickw(r, kh) : 0.f;
        den += w;
        qacc(alo, ahi, g, w * sc);
    }

    den += __shfl_xor(den, 32);
    float invk = den > 0.f ? 0.25f / den : 0.f;
    alo.x *= invk; alo.y *= invk; alo.z *= invk; alo.w *= invk;
    ahi.x *= invk; ahi.y *= invk; ahi.z *= invk; ahi.w *= invk;

#pragma unroll
    for (int off = 8; off < 64; off <<= 1) {
        alo.x += __shfl_xor(alo.x, off); alo.y += __shfl_xor(alo.y, off);
        alo.z += __shfl_xor(alo.z, off); alo.w += __shfl_xor(alo.w, off);
        ahi.x += __shfl_xor(ahi.x, off); ahi.y += __shfl_xor(ahi.y, off);
        ahi.z += __shfl_xor(ahi.z, off); ahi.w += __shfl_xor(ahi.w, off);
    }
    // permuted-layout epilogue: value m -> col (m&3)*16 + cg*2 + (m>>2)
    if (lane < 8) {
        float* op = out + (size_t)wid * OUT_DIM + (cg << 1);
        *(float2*)(op)      = make_float2(alo.x, ahi.x);
        *(float2*)(op + 16) = make_float2(alo.y, ahi.y);
        *(float2*)(op + 32) = make_float2(alo.z, ahi.z);
        *(float2*)(op + 48) = make_float2(alo.w, ahi.w);
    }
}

// ---------------------------------------------------------------------------
extern "C" void kernel_launch(void* const* d_in, const int* in_sizes, int n_in,
                              void* d_out, int out_size, void* d_ws, size_t ws_size,
                              hipStream_t stream) {
    const float* h     = (const float*)d_in[0];
    const int*   edges = (const int*)d_in[1];
    const float* W     = (const float*)d_in[2];
    const float* a     = (const float*)d_in[3];
    float* out = (float*)d_out;

    char* ws = (char*)d_ws;
    unsigned char* hw8 = (unsigned char*)(ws);          // 25,600,000 B [N][256] u8
    float*  scaleArr= (float*) (ws + 25600000);         //  1,600,000 B [N][4]
    float*  sArrS   = (float*) (ws + 27200000);         //  1,600,000 B
    float*  sArrD   = (float*) (ws + 28800000);         //  1,600,000 B
    short*  WcatT   = (short*) (ws + 30400000);         //     65,536 B
    float*  Wa      = (float*) (ws + 30465536);         //      4,096 B
    int*    cnt     = (int*)   (ws + 30469632);         //    400,000 B
    int*    rangeCnt= (int*)   (ws + 30869632);         //      1,024 B
    uint4*  csr     = (uint4*) (ws + 30870656);         // 76,800,000 B (~107.7MB)

    // dense per-range edge lists in d_out: 250*8192*4 = 8,192,000 B (<25.6MB)
    unsigned* dense = (unsigned*)d_out;

    hipMemsetAsync(rangeCnt, 0, NRANGE * sizeof(int), stream);

    prep_kernel<<<132, 256, 0, stream>>>(W, a, WcatT, Wa);
    s_bin<<<S_BLOCKS + CHUNKS, 256, 0, stream>>>(h, Wa, edges, dense, rangeCnt,
                                                 sArrS, sArrD);
    gemm_scatter<<<NRANGE + GEMM_BLOCKS, 256, 0, stream>>>(
        h, WcatT, dense, rangeCnt, (const float4*)sArrS, (const float4*)sArrD,
        cnt, csr, hw8, scaleArr);

    msg_csr<<<(N_NODES + 3) / 4, 256, 0, stream>>>(cnt, csr, hw8, scaleArr, out);
}

// Round 24
// 171.880 us; speedup vs baseline: 1.0207x; 1.0207x over previous
//
#include <hip/hip_runtime.h>
#include <hip/hip_fp16.h>

#define N_NODES 100000
#define N_EDGES 1600000
#define IN_DIM  128
#define OUT_DIM 64
#define HEADS   4
#define SLOPE   0.2f
#define CLIP_LO 0.005f
#define CLIP_HI 10.0f
#define NRANGE 250
#define RANGE_SZ 400         // N_NODES / NRANGE (exact)
#define EDGES_PER_BLK 2048   // 8 edges/thread * 256
#define CHUNKS 782           // ceil(N_EDGES / EDGES_PER_BLK)
#define GEMM_BLOCKS 1563     // ceil(N_NODES/64)
#define S_BLOCKS 391         // ceil(N_NODES/256)
#define BUCKET 48            // fixed per-dst CSR capacity
#define BIN_CAP 32           // per-(range,chunk) LDS bin capacity (mean 8.2)
#define CAPR 8192            // dense per-range list capacity (mean 6400)

typedef short bf16x8 __attribute__((ext_vector_type(8)));
typedef float f32x4  __attribute__((ext_vector_type(4)));

__device__ __forceinline__ short f2bf(float x) {
    union { float f; unsigned u; } v; v.f = x;
    unsigned r = (v.u + 0x7FFF + ((v.u >> 16) & 1)) >> 16;   // RNE
    return (short)r;
}
__device__ __forceinline__ unsigned short f2hbits(float x) {
    union { __half h; unsigned short u; } c; c.h = __float2half(x); return c.u;
}
__device__ __forceinline__ float hbits2f(unsigned short b) {
    union { __half h; unsigned short u; } c; c.u = b; return __half2float(c.h);
}

// ---------------------------------------------------------------------------
// prep: WcatT[n][i]=bf16(W[k][i][j]) (n=k*64+j) and Wa[k][half][i]
// ---------------------------------------------------------------------------
__global__ __launch_bounds__(256) void prep_kernel(const float* __restrict__ W,
                                                   const float* __restrict__ a,
                                                   short* __restrict__ WcatT,
                                                   float* __restrict__ Wa) {
    int idx = blockIdx.x * 256 + threadIdx.x;
    if (idx < 256 * 128) {
        int n = idx >> 7, i = idx & 127;
        int k = n >> 6, j = n & 63;
        WcatT[idx] = f2bf(W[((size_t)k * IN_DIM + i) * OUT_DIM + j]);
    } else if (idx < 256 * 128 + 1024) {
        int o = idx - 256 * 128;
        int k = o >> 8, half = (o >> 7) & 1, i = o & 127;
        const float* wrow = W + ((size_t)k * IN_DIM + i) * OUT_DIM;
        const float* av   = a + k * 2 * OUT_DIM + half * OUT_DIM;
        float acc = 0.f;
#pragma unroll 8
        for (int j = 0; j < OUT_DIM; ++j) acc += wrow[j] * av[j];
        Wa[o] = acc;
    }
}

// ---------------------------------------------------------------------------
// s_bin: blocks [0,S_BLOCKS) = exact-f32 scores; blocks [S_BLOCKS,+CHUNKS) =
// binning into 250 ranges -> dense per-range lists. (R23-proven)
// ---------------------------------------------------------------------------
__global__ __launch_bounds__(256) void s_bin(const float* __restrict__ h,
                                             const float* __restrict__ Wa,
                                             const int* __restrict__ edges,
                                             unsigned* __restrict__ dense,
                                             int* __restrict__ rangeCnt,
                                             float* __restrict__ sS,
                                             float* __restrict__ sD) {
    __shared__ __align__(16) char smem[35072];
    if (blockIdx.x >= S_BLOCKS) {
        int* bcnt = (int*)smem;
        unsigned* bents = (unsigned*)(smem + 1024);
        int* posL = (int*)(smem + 33024);
        const int c = blockIdx.x - S_BLOCKS;
        const int base = c * EDGES_PER_BLK + threadIdx.x * 8;
        for (int t = threadIdx.x; t < NRANGE; t += 256) bcnt[t] = 0;
        __syncthreads();
        if (base < N_EDGES) {
            int4 s0 = *(const int4*)(edges + base);
            int4 s1 = *(const int4*)(edges + base + 4);
            int4 d0 = *(const int4*)(edges + N_EDGES + base);
            int4 d1 = *(const int4*)(edges + N_EDGES + base + 4);
            int ss[8] = {s0.x, s0.y, s0.z, s0.w, s1.x, s1.y, s1.z, s1.w};
            int dd[8] = {d0.x, d0.y, d0.z, d0.w, d1.x, d1.y, d1.z, d1.w};
#pragma unroll
            for (int u = 0; u < 8; ++u) {
                unsigned d = (unsigned)dd[u];
                unsigned r = d / (unsigned)RANGE_SZ;
                int pos = atomicAdd(&bcnt[r], 1);
                if (pos < BIN_CAP)
                    bents[r * BIN_CAP + pos] = ((unsigned)ss[u] << 9) | (d - r * RANGE_SZ);
            }
        }
        __syncthreads();
        if (threadIdx.x < NRANGE) {
            int n = bcnt[threadIdx.x]; if (n > BIN_CAP) n = BIN_CAP;
            bcnt[threadIdx.x] = n;
            posL[threadIdx.x] = atomicAdd(&rangeCnt[threadIdx.x], n);
        }
        __syncthreads();
        for (int idx = threadIdx.x; idx < NRANGE * BIN_CAP; idx += 256) {
            int r = idx >> 5, i = idx & 31;
            if (i < bcnt[r]) {
                int p = posL[r] + i;
                if (p < CAPR) dense[(size_t)r * CAPR + p] = bents[r * BIN_CAP + i];
            }
        }
        return;
    }

    float* wa_s = (float*)smem;
    for (int t = threadIdx.x; t < HEADS * 2 * IN_DIM; t += 256) wa_s[t] = Wa[t];
    __syncthreads();
    int n = blockIdx.x * 256 + threadIdx.x;
    if (n >= N_NODES) return;
    const float4* hv = (const float4*)(h + (size_t)n * IN_DIM);
    const float4* wv = (const float4*)wa_s;
    float acc[8] = {0.f,0.f,0.f,0.f,0.f,0.f,0.f,0.f};
    for (int i4 = 0; i4 < IN_DIM / 4; ++i4) {
        float4 hx = hv[i4];
#pragma unroll
        for (int k2 = 0; k2 < 8; ++k2) {
            float4 w = wv[k2 * (IN_DIM / 4) + i4];
            acc[k2] += hx.x * w.x + hx.y * w.y + hx.z * w.z + hx.w * w.w;
        }
    }
    *(float4*)(sS + (size_t)n * 4) = make_float4(acc[0], acc[2], acc[4], acc[6]);
    *(float4*)(sD + (size_t)n * 4) = make_float4(acc[1], acc[3], acc[5], acc[7]);
}

// ---------------------------------------------------------------------------
__device__ __forceinline__ float edge_e(float x) {
    x = x > 0.f ? x : SLOPE * x;
    float ev = __expf(x);
    return fminf(fmaxf(ev, CLIP_LO), CLIP_HI);
}

// ---------------------------------------------------------------------------
// gemm_scatter: blocks [0,NRANGE) = range-owned scatter over dense lists;
// blocks [NRANGE,+GEMM_BLOCKS) = MFMA GEMM + int8 epilogue. (R23-proven)
// ---------------------------------------------------------------------------
__global__ __launch_bounds__(256) void gemm_scatter(const float* __restrict__ h,
                                                    const short* __restrict__ WcatT,
                                                    const unsigned* __restrict__ dense,
                                                    const int* __restrict__ rangeCnt,
                                                    const float4* __restrict__ sArrS,
                                                    const float4* __restrict__ sArrD,
                                                    int* __restrict__ cnt,
                                                    uint4* __restrict__ csr,
                                                    unsigned char* __restrict__ hw8,
                                                    float* __restrict__ scaleArr) {
    __shared__ __align__(16) char smem[64 * 136 * 2];

    if (blockIdx.x < NRANGE) {
        int*    cntL = (int*)smem;
        float4* dvL  = (float4*)(smem + 1664);
        const int r = blockIdx.x;
        for (int t = threadIdx.x; t < RANGE_SZ; t += 256) {
            cntL[t] = 0;
            dvL[t]  = sArrD[r * RANGE_SZ + t];
        }
        __syncthreads();

        int n = rangeCnt[r]; if (n > CAPR) n = CAPR;
        const unsigned* dl = dense + (size_t)r * CAPR;
        for (int i0 = threadIdx.x * 4; i0 < n; i0 += 1024) {
            uint4 e4 = *(const uint4*)(dl + i0);
            unsigned ent[4] = {e4.x, e4.y, e4.z, e4.w};
            int nv = n - i0; if (nv > 4) nv = 4;
            float4 sv[4], dv[4];
#pragma unroll
            for (int u = 0; u < 4; ++u) {
                if (u < nv) {
                    sv[u] = sArrS[ent[u] >> 9];
                    dv[u] = dvL[ent[u] & 511];
                }
            }
#pragma unroll
            for (int u = 0; u < 4; ++u) {
                if (u < nv) {
                    int s  = ent[u] >> 9;
                    int dloc = ent[u] & 511;
                    uint4 rec;
                    rec.x = (unsigned)s;
                    rec.y = f2hbits(edge_e(sv[u].x + dv[u].x)) | ((unsigned)f2hbits(edge_e(sv[u].y + dv[u].y)) << 16);
                    rec.z = f2hbits(edge_e(sv[u].z + dv[u].z)) | ((unsigned)f2hbits(edge_e(sv[u].w + dv[u].w)) << 16);
                    rec.w = 0;
                    int pos = atomicAdd(&cntL[dloc], 1);
                    if (pos < BUCKET)
                        csr[(size_t)(r * RANGE_SZ + dloc) * BUCKET + pos] = rec;
                }
            }
        }
        __syncthreads();
        for (int t = threadIdx.x; t < RANGE_SZ; t += 256) {
            int v = cntL[t];
            cnt[r * RANGE_SZ + t] = v > BUCKET ? BUCKET : v;
        }
        return;
    }

    // ---- GEMM + int8 epilogue ----
    short (*As)[136] = (short(*)[136])smem;
    const int row0 = (blockIdx.x - NRANGE) * 64;
    const int tid  = threadIdx.x;

#pragma unroll
    for (int u = 0; u < 4; ++u) {
        int e = (tid + u * 256) * 8;
        int r = e >> 7, c = e & 127;
        int grow = row0 + r; if (grow >= N_NODES) grow = N_NODES - 1;
        const float* hp = h + (size_t)grow * IN_DIM + c;
        float4 v0 = *(const float4*)hp;
        float4 v1 = *(const float4*)(hp + 4);
        bf16x8 b;
        b[0]=f2bf(v0.x); b[1]=f2bf(v0.y); b[2]=f2bf(v0.z); b[3]=f2bf(v0.w);
        b[4]=f2bf(v1.x); b[5]=f2bf(v1.y); b[6]=f2bf(v1.z); b[7]=f2bf(v1.w);
        *(bf16x8*)&As[r][c] = b;
    }
    __syncthreads();

    const int wv = tid >> 6, lane = tid & 63;
    const int lrow = lane & 15;
    const int lk   = (lane >> 4) * 8;

    bf16x8 bfr[4][4];
#pragma unroll
    for (int nt = 0; nt < 4; ++nt)
#pragma unroll
        for (int ks = 0; ks < 4; ++ks)
            bfr[nt][ks] = *(const bf16x8*)(WcatT + (size_t)(wv * 64 + nt * 16 + lrow) * 128 + ks * 32 + lk);

    f32x4 acc[4][4] = {};
#pragma unroll
    for (int ks = 0; ks < 4; ++ks) {
        bf16x8 afr[4];
#pragma unroll
        for (int mt = 0; mt < 4; ++mt)
            afr[mt] = *(const bf16x8*)&As[mt * 16 + lrow][ks * 32 + lk];
#pragma unroll
        for (int mt = 0; mt < 4; ++mt)
#pragma unroll
            for (int nt = 0; nt < 4; ++nt)
                acc[mt][nt] = __builtin_amdgcn_mfma_f32_16x16x32_bf16(afr[mt], bfr[nt][ks], acc[mt][nt], 0, 0, 0);
    }

    const int rgrp = lane >> 4;
#pragma unroll
    for (int mt = 0; mt < 4; ++mt)
#pragma unroll
        for (int reg = 0; reg < 4; ++reg) {
            int g = row0 + mt * 16 + rgrp * 4 + reg;
            float m = fmaxf(fmaxf(fabsf(acc[mt][0][reg]), fabsf(acc[mt][1][reg])),
                            fmaxf(fabsf(acc[mt][2][reg]), fabsf(acc[mt][3][reg])));
#pragma unroll
            for (int off = 1; off < 16; off <<= 1)
                m = fmaxf(m, __shfl_xor(m, off));
            float scale = m > 0.f ? m * (1.f / 127.f) : 1.f;
            float inv   = m > 0.f ? 127.f / m : 0.f;
            uchar4 q;
            q.x = (unsigned char)(int)rintf(acc[mt][0][reg] * inv + 128.f);
            q.y = (unsigned char)(int)rintf(acc[mt][1][reg] * inv + 128.f);
            q.z = (unsigned char)(int)rintf(acc[mt][2][reg] * inv + 128.f);
            q.w = (unsigned char)(int)rintf(acc[mt][3][reg] * inv + 128.f);
            if (g < N_NODES) {
                *(uchar4*)(hw8 + (size_t)g * 256 + wv * 64 + lrow * 4) = q;
                if (lrow == 0) scaleArr[(size_t)g * 4 + wv] = scale;
            }
        }
}

// ---------------------------------------------------------------------------
__device__ __forceinline__ float pickw(const uint4& r, int kh) {
    unsigned wp = (kh & 2) ? r.z : r.y;
    return hbits2f((unsigned short)((kh & 1) ? (wp >> 16) : (wp & 0xffff)));
}
// int8 accumulate, bias-free: acc += ws*v (1 fma/value); bias handled via wssum
__device__ __forceinline__ void qacc(float4& lo, float4& hi, uint2 g, float ws) {
    unsigned x = g.x, y = g.y;
    lo.x = fmaf((float)( x        & 255u), ws, lo.x);
    lo.y = fmaf((float)((x >> 8 ) & 255u), ws, lo.y);
    lo.z = fmaf((float)((x >> 16) & 255u), ws, lo.z);
    lo.w = fmaf((float)( x >> 24        ), ws, lo.w);
    hi.x = fmaf((float)( y        & 255u), ws, hi.x);
    hi.y = fmaf((float)((y >> 8 ) & 255u), ws, hi.y);
    hi.z = fmaf((float)((y >> 16) & 255u), ws, hi.z);
    hi.w = fmaf((float)( y >> 24        ), ws, hi.w);
}

// msg_csr over int8 hw, bias-folded: out = (Σ ws·v − 128·Σ ws) / den / 4
__global__ __launch_bounds__(256) void msg_csr(const int* __restrict__ cnt,
                                               const uint4* __restrict__ csr,
                                               const unsigned char* __restrict__ hw8,
                                               const float* __restrict__ scaleArr,
                                               float* __restrict__ out) {
    int wid  = (blockIdx.x * 256 + threadIdx.x) >> 6;
    int lane = threadIdx.x & 63;
    if (wid >= N_NODES) return;
    const size_t start = (size_t)wid * BUCKET;
    int dg = cnt[wid];
    if (dg > BUCKET) dg = BUCKET;

    const int es = lane >> 5;
    const int kh = (lane & 31) >> 3;
    const int cg = lane & 7;
    const size_t coff = (size_t)((kh << 6) + (cg << 3));

    float4 alo = make_float4(0.f,0.f,0.f,0.f), ahi = make_float4(0.f,0.f,0.f,0.f);
    float den = 0.f, wssum = 0.f;
    int i = 0;
    for (; i + 8 <= dg; i += 8) {
        uint4 r0 = csr[start + i     + es];
        uint4 r1 = csr[start + i + 2 + es];
        uint4 r2 = csr[start + i + 4 + es];
        uint4 r3 = csr[start + i + 6 + es];
        uint2 g0 = *(const uint2*)(hw8 + (((size_t)r0.x) << 8) + coff);
        uint2 g1 = *(const uint2*)(hw8 + (((size_t)r1.x) << 8) + coff);
        uint2 g2 = *(const uint2*)(hw8 + (((size_t)r2.x) << 8) + coff);
        uint2 g3 = *(const uint2*)(hw8 + (((size_t)r3.x) << 8) + coff);
        float sc0 = scaleArr[(size_t)r0.x * 4 + kh];
        float sc1 = scaleArr[(size_t)r1.x * 4 + kh];
        float sc2 = scaleArr[(size_t)r2.x * 4 + kh];
        float sc3 = scaleArr[(size_t)r3.x * 4 + kh];
        float w0 = pickw(r0, kh);
        float w1 = pickw(r1, kh);
        float w2 = pickw(r2, kh);
        float w3 = pickw(r3, kh);
        den += (w0 + w1) + (w2 + w3);
        float ws0 = w0 * sc0, ws1 = w1 * sc1, ws2 = w2 * sc2, ws3 = w3 * sc3;
        wssum += (ws0 + ws1) + (ws2 + ws3);
        qacc(alo, ahi, g0, ws0);
        qacc(alo, ahi, g1, ws1);
        qacc(alo, ahi, g2, ws2);
        qacc(alo, ahi, g3, ws3);
    }
    for (; i + 4 <= dg; i += 4) {
        uint4 r0 = csr[start + i     + es];
        uint4 r1 = csr[start + i + 2 + es];
        uint2 g0 = *(const uint2*)(hw8 + (((size_t)r0.x) << 8) + coff);
        uint2 g1 = *(const uint2*)(hw8 + (((size_t)r1.x) << 8) + coff);
        float sc0 = scaleArr[(size_t)r0.x * 4 + kh];
        float sc1 = scaleArr[(size_t)r1.x * 4 + kh];
        float w0 = pickw(r0, kh);
        float w1 = pickw(r1, kh);
        den += w0 + w1;
        float ws0 = w0 * sc0, ws1 = w1 * sc1;
        wssum += ws0 + ws1;
        qacc(alo, ahi, g0, ws0);
        qacc(alo, ahi, g1, ws1);
    }
    for (; i < dg; i += 2) {
        int idx = i + es;
        bool valid = idx < dg;
        if (idx >= dg) idx = dg - 1;
        uint4 r = csr[start + idx];
        uint2 g = *(const uint2*)(hw8 + (((size_t)r.x) << 8) + coff);
        float sc = scaleArr[(size_t)r.x * 4 + kh];
        float w = valid ? pickw(r, kh) : 0.f;
        den += w;
        float ws = w * sc;
        wssum += ws;
        qacc(alo, ahi, g, ws);
    }

    // remove bias: acc -= 128*wssum
    {
        float b = 128.f * wssum;
        alo.x -= b; alo.y -= b; alo.z -= b; alo.w -= b;
        ahi.x -= b; ahi.y -= b; ahi.z -= b; ahi.w -= b;
    }

    den += __shfl_xor(den, 32);
    float invk = den > 0.f ? 0.25f / den : 0.f;
    alo.x *= invk; alo.y *= invk; alo.z *= invk; alo.w *= invk;
    ahi.x *= invk; ahi.y *= invk; ahi.z *= invk; ahi.w *= invk;

#pragma unroll
    for (int off = 8; off < 64; off <<= 1) {
        alo.x += __shfl_xor(alo.x, off); alo.y += __shfl_xor(alo.y, off);
        alo.z += __shfl_xor(alo.z, off); alo.w += __shfl_xor(alo.w, off);
        ahi.x += __shfl_xor(ahi.x, off); ahi.y += __shfl_xor(ahi.y, off);
        ahi.z += __shfl_xor(ahi.z, off); ahi.w += __shfl_xor(ahi.w, off);
    }
    // permuted-layout epilogue: value m -> col (m&3)*16 + cg*2 + (m>>2)
    if (lane < 8) {
        float* op = out + (size_t)wid * OUT_DIM + (cg << 1);
        *(float2*)(op)      = make_float2(alo.x, ahi.x);
        *(float2*)(op + 16) = make_float2(alo.y, ahi.y);
        *(float2*)(op + 32) = make_float2(alo.z, ahi.z);
        *(float2*)(op + 48) = make_float2(alo.w, ahi.w);
    }
}

// ---------------------------------------------------------------------------
extern "C" void kernel_launch(void* const* d_in, const int* in_sizes, int n_in,
                              void* d_out, int out_size, void* d_ws, size_t ws_size,
                              hipStream_t stream) {
    const float* h     = (const float*)d_in[0];
    const int*   edges = (const int*)d_in[1];
    const float* W     = (const float*)d_in[2];
    const float* a     = (const float*)d_in[3];
    float* out = (float*)d_out;

    char* ws = (char*)d_ws;
    unsigned char* hw8 = (unsigned char*)(ws);          // 25,600,000 B [N][256] u8
    float*  scaleArr= (float*) (ws + 25600000);         //  1,600,000 B [N][4]
    float*  sArrS   = (float*) (ws + 27200000);         //  1,600,000 B
    float*  sArrD   = (float*) (ws + 28800000);         //  1,600,000 B
    short*  WcatT   = (short*) (ws + 30400000);         //     65,536 B
    float*  Wa      = (float*) (ws + 30465536);         //      4,096 B
    int*    cnt     = (int*)   (ws + 30469632);         //    400,000 B
    int*    rangeCnt= (int*)   (ws + 30869632);         //      1,024 B
    uint4*  csr     = (uint4*) (ws + 30870656);         // 76,800,000 B (~107.7MB)

    // dense per-range edge lists in d_out: 250*8192*4 = 8,192,000 B (<25.6MB)
    unsigned* dense = (unsigned*)d_out;

    hipMemsetAsync(rangeCnt, 0, NRANGE * sizeof(int), stream);

    prep_kernel<<<132, 256, 0, stream>>>(W, a, WcatT, Wa);
    s_bin<<<S_BLOCKS + CHUNKS, 256, 0, stream>>>(h, Wa, edges, dense, rangeCnt,
                                                 sArrS, sArrD);
    gemm_scatter<<<NRANGE + GEMM_BLOCKS, 256, 0, stream>>>(
        h, WcatT, dense, rangeCnt, (const float4*)sArrS, (const float4*)sArrD,
        cnt, csr, hw8, scaleArr);

    msg_csr<<<(N_NODES + 3) / 4, 256, 0, stream>>>(cnt, csr, hw8, scaleArr, out);
}

// Round 25
// 171.625 us; speedup vs baseline: 1.0222x; 1.0015x over previous
//
#include <hip/hip_runtime.h>
#include <hip/hip_fp16.h>

#define N_NODES 100000
#define N_EDGES 1600000
#define IN_DIM  128
#define OUT_DIM 64
#define HEADS   4
#define SLOPE   0.2f
#define CLIP_LO 0.005f
#define CLIP_HI 10.0f
#define NRANGE 250
#define RANGE_SZ 400         // N_NODES / NRANGE (exact)
#define EDGES_PER_BLK 2048   // 8 edges/thread * 256
#define CHUNKS 782           // ceil(N_EDGES / EDGES_PER_BLK)
#define GEMM_BLOCKS 1563     // ceil(N_NODES/64)
#define S_BLOCKS 391         // ceil(N_NODES/256)
#define BUCKET 48            // fixed per-dst CSR capacity
#define BIN_CAP 32           // per-(range,chunk) LDS bin capacity (mean 8.2)
#define CAPR 8192            // dense per-range list capacity (mean 6400)

typedef short bf16x8 __attribute__((ext_vector_type(8)));
typedef float f32x4  __attribute__((ext_vector_type(4)));

__device__ __forceinline__ short f2bf(float x) {
    union { float f; unsigned u; } v; v.f = x;
    unsigned r = (v.u + 0x7FFF + ((v.u >> 16) & 1)) >> 16;   // RNE
    return (short)r;
}
__device__ __forceinline__ unsigned short f2hbits(float x) {
    union { __half h; unsigned short u; } c; c.h = __float2half(x); return c.u;
}
__device__ __forceinline__ float hbits2f(unsigned short b) {
    union { __half h; unsigned short u; } c; c.u = b; return __half2float(c.h);
}

// ---------------------------------------------------------------------------
// prep: WcatT[n][i]=bf16(W[k][i][j]) (n=k*64+j) and Wa[k][half][i]
// ---------------------------------------------------------------------------
__global__ __launch_bounds__(256) void prep_kernel(const float* __restrict__ W,
                                                   const float* __restrict__ a,
                                                   short* __restrict__ WcatT,
                                                   float* __restrict__ Wa) {
    int idx = blockIdx.x * 256 + threadIdx.x;
    if (idx < 256 * 128) {
        int n = idx >> 7, i = idx & 127;
        int k = n >> 6, j = n & 63;
        WcatT[idx] = f2bf(W[((size_t)k * IN_DIM + i) * OUT_DIM + j]);
    } else if (idx < 256 * 128 + 1024) {
        int o = idx - 256 * 128;
        int k = o >> 8, half = (o >> 7) & 1, i = o & 127;
        const float* wrow = W + ((size_t)k * IN_DIM + i) * OUT_DIM;
        const float* av   = a + k * 2 * OUT_DIM + half * OUT_DIM;
        float acc = 0.f;
#pragma unroll 8
        for (int j = 0; j < OUT_DIM; ++j) acc += wrow[j] * av[j];
        Wa[o] = acc;
    }
}

// ---------------------------------------------------------------------------
// s_bin: blocks [0,S_BLOCKS) = exact-f32 scores; blocks [S_BLOCKS,+CHUNKS) =
// binning into 250 ranges -> dense per-range lists. (R23-proven)
// ---------------------------------------------------------------------------
__global__ __launch_bounds__(256) void s_bin(const float* __restrict__ h,
                                             const float* __restrict__ Wa,
                                             const int* __restrict__ edges,
                                             unsigned* __restrict__ dense,
                                             int* __restrict__ rangeCnt,
                                             float* __restrict__ sS,
                                             float* __restrict__ sD) {
    __shared__ __align__(16) char smem[35072];
    if (blockIdx.x >= S_BLOCKS) {
        int* bcnt = (int*)smem;
        unsigned* bents = (unsigned*)(smem + 1024);
        int* posL = (int*)(smem + 33024);
        const int c = blockIdx.x - S_BLOCKS;
        const int base = c * EDGES_PER_BLK + threadIdx.x * 8;
        for (int t = threadIdx.x; t < NRANGE; t += 256) bcnt[t] = 0;
        __syncthreads();
        if (base < N_EDGES) {
            int4 s0 = *(const int4*)(edges + base);
            int4 s1 = *(const int4*)(edges + base + 4);
            int4 d0 = *(const int4*)(edges + N_EDGES + base);
            int4 d1 = *(const int4*)(edges + N_EDGES + base + 4);
            int ss[8] = {s0.x, s0.y, s0.z, s0.w, s1.x, s1.y, s1.z, s1.w};
            int dd[8] = {d0.x, d0.y, d0.z, d0.w, d1.x, d1.y, d1.z, d1.w};
#pragma unroll
            for (int u = 0; u < 8; ++u) {
                unsigned d = (unsigned)dd[u];
                unsigned r = d / (unsigned)RANGE_SZ;
                int pos = atomicAdd(&bcnt[r], 1);
                if (pos < BIN_CAP)
                    bents[r * BIN_CAP + pos] = ((unsigned)ss[u] << 9) | (d - r * RANGE_SZ);
            }
        }
        __syncthreads();
        if (threadIdx.x < NRANGE) {
            int n = bcnt[threadIdx.x]; if (n > BIN_CAP) n = BIN_CAP;
            bcnt[threadIdx.x] = n;
            posL[threadIdx.x] = atomicAdd(&rangeCnt[threadIdx.x], n);
        }
        __syncthreads();
        for (int idx = threadIdx.x; idx < NRANGE * BIN_CAP; idx += 256) {
            int r = idx >> 5, i = idx & 31;
            if (i < bcnt[r]) {
                int p = posL[r] + i;
                if (p < CAPR) dense[(size_t)r * CAPR + p] = bents[r * BIN_CAP + i];
            }
        }
        return;
    }

    float* wa_s = (float*)smem;
    for (int t = threadIdx.x; t < HEADS * 2 * IN_DIM; t += 256) wa_s[t] = Wa[t];
    __syncthreads();
    int n = blockIdx.x * 256 + threadIdx.x;
    if (n >= N_NODES) return;
    const float4* hv = (const float4*)(h + (size_t)n * IN_DIM);
    const float4* wv = (const float4*)wa_s;
    float acc[8] = {0.f,0.f,0.f,0.f,0.f,0.f,0.f,0.f};
    for (int i4 = 0; i4 < IN_DIM / 4; ++i4) {
        float4 hx = hv[i4];
#pragma unroll
        for (int k2 = 0; k2 < 8; ++k2) {
            float4 w = wv[k2 * (IN_DIM / 4) + i4];
            acc[k2] += hx.x * w.x + hx.y * w.y + hx.z * w.z + hx.w * w.w;
        }
    }
    *(float4*)(sS + (size_t)n * 4) = make_float4(acc[0], acc[2], acc[4], acc[6]);
    *(float4*)(sD + (size_t)n * 4) = make_float4(acc[1], acc[3], acc[5], acc[7]);
}

// ---------------------------------------------------------------------------
__device__ __forceinline__ float edge_e(float x) {
    x = x > 0.f ? x : SLOPE * x;
    float ev = __expf(x);
    return fminf(fmaxf(ev, CLIP_LO), CLIP_HI);
}

// ---------------------------------------------------------------------------
// gemm_scatter: blocks [0,NRANGE) = range-owned scatter over dense lists;
// blocks [NRANGE,+GEMM_BLOCKS) = MFMA GEMM + int8 epilogue. (R23-proven)
// ---------------------------------------------------------------------------
__global__ __launch_bounds__(256) void gemm_scatter(const float* __restrict__ h,
                                                    const short* __restrict__ WcatT,
                                                    const unsigned* __restrict__ dense,
                                                    const int* __restrict__ rangeCnt,
                                                    const float4* __restrict__ sArrS,
                                                    const float4* __restrict__ sArrD,
                                                    int* __restrict__ cnt,
                                                    uint4* __restrict__ csr,
                                                    unsigned char* __restrict__ hw8,
                                                    float* __restrict__ scaleArr) {
    __shared__ __align__(16) char smem[64 * 136 * 2];

    if (blockIdx.x < NRANGE) {
        int*    cntL = (int*)smem;
        float4* dvL  = (float4*)(smem + 1664);
        const int r = blockIdx.x;
        for (int t = threadIdx.x; t < RANGE_SZ; t += 256) {
            cntL[t] = 0;
            dvL[t]  = sArrD[r * RANGE_SZ + t];
        }
        __syncthreads();

        int n = rangeCnt[r]; if (n > CAPR) n = CAPR;
        const unsigned* dl = dense + (size_t)r * CAPR;
        for (int i0 = threadIdx.x * 4; i0 < n; i0 += 1024) {
            uint4 e4 = *(const uint4*)(dl + i0);
            unsigned ent[4] = {e4.x, e4.y, e4.z, e4.w};
            int nv = n - i0; if (nv > 4) nv = 4;
            float4 sv[4], dv[4];
#pragma unroll
            for (int u = 0; u < 4; ++u) {
                if (u < nv) {
                    sv[u] = sArrS[ent[u] >> 9];
                    dv[u] = dvL[ent[u] & 511];
                }
            }
#pragma unroll
            for (int u = 0; u < 4; ++u) {
                if (u < nv) {
                    int s  = ent[u] >> 9;
                    int dloc = ent[u] & 511;
                    uint4 rec;
                    rec.x = (unsigned)s;
                    rec.y = f2hbits(edge_e(sv[u].x + dv[u].x)) | ((unsigned)f2hbits(edge_e(sv[u].y + dv[u].y)) << 16);
                    rec.z = f2hbits(edge_e(sv[u].z + dv[u].z)) | ((unsigned)f2hbits(edge_e(sv[u].w + dv[u].w)) << 16);
                    rec.w = 0;
                    int pos = atomicAdd(&cntL[dloc], 1);
                    if (pos < BUCKET)
                        csr[(size_t)(r * RANGE_SZ + dloc) * BUCKET + pos] = rec;
                }
            }
        }
        __syncthreads();
        for (int t = threadIdx.x; t < RANGE_SZ; t += 256) {
            int v = cntL[t];
            cnt[r * RANGE_SZ + t] = v > BUCKET ? BUCKET : v;
        }
        return;
    }

    // ---- GEMM + int8 epilogue ----
    short (*As)[136] = (short(*)[136])smem;
    const int row0 = (blockIdx.x - NRANGE) * 64;
    const int tid  = threadIdx.x;

#pragma unroll
    for (int u = 0; u < 4; ++u) {
        int e = (tid + u * 256) * 8;
        int r = e >> 7, c = e & 127;
        int grow = row0 + r; if (grow >= N_NODES) grow = N_NODES - 1;
        const float* hp = h + (size_t)grow * IN_DIM + c;
        float4 v0 = *(const float4*)hp;
        float4 v1 = *(const float4*)(hp + 4);
        bf16x8 b;
        b[0]=f2bf(v0.x); b[1]=f2bf(v0.y); b[2]=f2bf(v0.z); b[3]=f2bf(v0.w);
        b[4]=f2bf(v1.x); b[5]=f2bf(v1.y); b[6]=f2bf(v1.z); b[7]=f2bf(v1.w);
        *(bf16x8*)&As[r][c] = b;
    }
    __syncthreads();

    const int wv = tid >> 6, lane = tid & 63;
    const int lrow = lane & 15;
    const int lk   = (lane >> 4) * 8;

    bf16x8 bfr[4][4];
#pragma unroll
    for (int nt = 0; nt < 4; ++nt)
#pragma unroll
        for (int ks = 0; ks < 4; ++ks)
            bfr[nt][ks] = *(const bf16x8*)(WcatT + (size_t)(wv * 64 + nt * 16 + lrow) * 128 + ks * 32 + lk);

    f32x4 acc[4][4] = {};
#pragma unroll
    for (int ks = 0; ks < 4; ++ks) {
        bf16x8 afr[4];
#pragma unroll
        for (int mt = 0; mt < 4; ++mt)
            afr[mt] = *(const bf16x8*)&As[mt * 16 + lrow][ks * 32 + lk];
#pragma unroll
        for (int mt = 0; mt < 4; ++mt)
#pragma unroll
            for (int nt = 0; nt < 4; ++nt)
                acc[mt][nt] = __builtin_amdgcn_mfma_f32_16x16x32_bf16(afr[mt], bfr[nt][ks], acc[mt][nt], 0, 0, 0);
    }

    const int rgrp = lane >> 4;
#pragma unroll
    for (int mt = 0; mt < 4; ++mt)
#pragma unroll
        for (int reg = 0; reg < 4; ++reg) {
            int g = row0 + mt * 16 + rgrp * 4 + reg;
            float m = fmaxf(fmaxf(fabsf(acc[mt][0][reg]), fabsf(acc[mt][1][reg])),
                            fmaxf(fabsf(acc[mt][2][reg]), fabsf(acc[mt][3][reg])));
#pragma unroll
            for (int off = 1; off < 16; off <<= 1)
                m = fmaxf(m, __shfl_xor(m, off));
            float scale = m > 0.f ? m * (1.f / 127.f) : 1.f;
            float inv   = m > 0.f ? 127.f / m : 0.f;
            uchar4 q;
            q.x = (unsigned char)(int)rintf(acc[mt][0][reg] * inv + 128.f);
            q.y = (unsigned char)(int)rintf(acc[mt][1][reg] * inv + 128.f);
            q.z = (unsigned char)(int)rintf(acc[mt][2][reg] * inv + 128.f);
            q.w = (unsigned char)(int)rintf(acc[mt][3][reg] * inv + 128.f);
            if (g < N_NODES) {
                *(uchar4*)(hw8 + (size_t)g * 256 + wv * 64 + lrow * 4) = q;
                if (lrow == 0) scaleArr[(size_t)g * 4 + wv] = scale;
            }
        }
}

// ---------------------------------------------------------------------------
__device__ __forceinline__ float pickw(const uint4& r, int kh) {
    unsigned wp = (kh & 2) ? r.z : r.y;
    return hbits2f((unsigned short)((kh & 1) ? (wp >> 16) : (wp & 0xffff)));
}
// int8 accumulate, bias-free: acc += ws*v (1 fma/value); bias handled via wssum
__device__ __forceinline__ void qacc(float4& lo, float4& hi, uint2 g, float ws) {
    unsigned x = g.x, y = g.y;
    lo.x = fmaf((float)( x        & 255u), ws, lo.x);
    lo.y = fmaf((float)((x >> 8 ) & 255u), ws, lo.y);
    lo.z = fmaf((float)((x >> 16) & 255u), ws, lo.z);
    lo.w = fmaf((float)( x >> 24        ), ws, lo.w);
    hi.x = fmaf((float)( y        & 255u), ws, hi.x);
    hi.y = fmaf((float)((y >> 8 ) & 255u), ws, hi.y);
    hi.z = fmaf((float)((y >> 16) & 255u), ws, hi.z);
    hi.w = fmaf((float)( y >> 24        ), ws, hi.w);
}

// msg_csr over int8 hw, bias-folded: out = (Σ ws·v − 128·Σ ws) / den / 4
__global__ __launch_bounds__(256) void msg_csr(const int* __restrict__ cnt,
                                               const uint4* __restrict__ csr,
                                               const unsigned char* __restrict__ hw8,
                                               const float* __restrict__ scaleArr,
                                               float* __restrict__ out) {
    int wid  = (blockIdx.x * 256 + threadIdx.x) >> 6;
    int lane = threadIdx.x & 63;
    if (wid >= N_NODES) return;
    const size_t start = (size_t)wid * BUCKET;
    int dg = cnt[wid];
    if (dg > BUCKET) dg = BUCKET;

    const int es = lane >> 5;
    const int kh = (lane & 31) >> 3;
    const int cg = lane & 7;
    const size_t coff = (size_t)((kh << 6) + (cg << 3));

    float4 alo = make_float4(0.f,0.f,0.f,0.f), ahi = make_float4(0.f,0.f,0.f,0.f);
    float den = 0.f, wssum = 0.f;
    int i = 0;
    for (; i + 8 <= dg; i += 8) {
        uint4 r0 = csr[start + i     + es];
        uint4 r1 = csr[start + i + 2 + es];
        uint4 r2 = csr[start + i + 4 + es];
        uint4 r3 = csr[start + i + 6 + es];
        uint2 g0 = *(const uint2*)(hw8 + (((size_t)r0.x) << 8) + coff);
        uint2 g1 = *(const uint2*)(hw8 + (((size_t)r1.x) << 8) + coff);
        uint2 g2 = *(const uint2*)(hw8 + (((size_t)r2.x) << 8) + coff);
        uint2 g3 = *(const uint2*)(hw8 + (((size_t)r3.x) << 8) + coff);
        float sc0 = scaleArr[(size_t)r0.x * 4 + kh];
        float sc1 = scaleArr[(size_t)r1.x * 4 + kh];
        float sc2 = scaleArr[(size_t)r2.x * 4 + kh];
        float sc3 = scaleArr[(size_t)r3.x * 4 + kh];
        float w0 = pickw(r0, kh);
        float w1 = pickw(r1, kh);
        float w2 = pickw(r2, kh);
        float w3 = pickw(r3, kh);
        den += (w0 + w1) + (w2 + w3);
        float ws0 = w0 * sc0, ws1 = w1 * sc1, ws2 = w2 * sc2, ws3 = w3 * sc3;
        wssum += (ws0 + ws1) + (ws2 + ws3);
        qacc(alo, ahi, g0, ws0);
        qacc(alo, ahi, g1, ws1);
        qacc(alo, ahi, g2, ws2);
        qacc(alo, ahi, g3, ws3);
    }
    for (; i + 4 <= dg; i += 4) {
        uint4 r0 = csr[start + i     + es];
        uint4 r1 = csr[start + i + 2 + es];
        uint2 g0 = *(const uint2*)(hw8 + (((size_t)r0.x) << 8) + coff);
        uint2 g1 = *(const uint2*)(hw8 + (((size_t)r1.x) << 8) + coff);
        float sc0 = scaleArr[(size_t)r0.x * 4 + kh];
        float sc1 = scaleArr[(size_t)r1.x * 4 + kh];
        float w0 = pickw(r0, kh);
        float w1 = pickw(r1, kh);
        den += w0 + w1;
        float ws0 = w0 * sc0, ws1 = w1 * sc1;
        wssum += ws0 + ws1;
        qacc(alo, ahi, g0, ws0);
        qacc(alo, ahi, g1, ws1);
    }
    for (; i < dg; i += 2) {
        int idx = i + es;
        bool valid = idx < dg;
        if (idx >= dg) idx = dg - 1;
        uint4 r = csr[start + idx];
        uint2 g = *(const uint2*)(hw8 + (((size_t)r.x) << 8) + coff);
        float sc = scaleArr[(size_t)r.x * 4 + kh];
        float w = valid ? pickw(r, kh) : 0.f;
        den += w;
        float ws = w * sc;
        wssum += ws;
        qacc(alo, ahi, g, ws);
    }

    // remove bias: acc -= 128*wssum
    {
        float b = 128.f * wssum;
        alo.x -= b; alo.y -= b; alo.z -= b; alo.w -= b;
        ahi.x -= b; ahi.y -= b; ahi.z -= b; ahi.w -= b;
    }

    den += __shfl_xor(den, 32);
    float invk = den > 0.f ? 0.25f / den : 0.f;
    alo.x *= invk; alo.y *= invk; alo.z *= invk; alo.w *= invk;
    ahi.x *= invk; ahi.y *= invk; ahi.z *= invk; ahi.w *= invk;

#pragma unroll
    for (int off = 8; off < 64; off <<= 1) {
        alo.x += __shfl_xor(alo.x, off); alo.y += __shfl_xor(alo.y, off);
        alo.z += __shfl_xor(alo.z, off); alo.w += __shfl_xor(alo.w, off);
        ahi.x += __shfl_xor(ahi.x, off); ahi.y += __shfl_xor(ahi.y, off);
        ahi.z += __shfl_xor(ahi.z, off); ahi.w += __shfl_xor(ahi.w, off);
    }
    // permuted-layout epilogue: value m -> col (m&3)*16 + cg*2 + (m>>2)
    if (lane < 8) {
        float* op = out + (size_t)wid * OUT_DIM + (cg << 1);
        *(float2*)(op)      = make_float2(alo.x, ahi.x);
        *(float2*)(op + 16) = make_float2(alo.y, ahi.y);
        *(float2*)(op + 32) = make_float2(alo.z, ahi.z);
        *(float2*)(op + 48) = make_float2(alo.w, ahi.w);
    }
}

// ---------------------------------------------------------------------------
extern "C" void kernel_launch(void* const* d_in, const int* in_sizes, int n_in,
                              void* d_out, int out_size, void* d_ws, size_t ws_size,
                              hipStream_t stream) {
    const float* h     = (const float*)d_in[0];
    const int*   edges = (const int*)d_in[1];
    const float* W     = (const float*)d_in[2];
    const float* a     = (const float*)d_in[3];
    float* out = (float*)d_out;

    char* ws = (char*)d_ws;
    unsigned char* hw8 = (unsigned char*)(ws);          // 25,600,000 B [N][256] u8
    float*  scaleArr= (float*) (ws + 25600000);         //  1,600,000 B [N][4]
    float*  sArrS   = (float*) (ws + 27200000);         //  1,600,000 B
    float*  sArrD   = (float*) (ws + 28800000);         //  1,600,000 B
    short*  WcatT   = (short*) (ws + 30400000);         //     65,536 B
    float*  Wa      = (float*) (ws + 30465536);         //      4,096 B
    int*    cnt     = (int*)   (ws + 30469632);         //    400,000 B
    int*    rangeCnt= (int*)   (ws + 30869632);         //      1,024 B
    uint4*  csr     = (uint4*) (ws + 30870656);         // 76,800,000 B (~107.7MB)

    // dense per-range edge lists in d_out: 250*8192*4 = 8,192,000 B (<25.6MB)
    unsigned* dense = (unsigned*)d_out;

    hipMemsetAsync(rangeCnt, 0, NRANGE * sizeof(int), stream);

    prep_kernel<<<132, 256, 0, stream>>>(W, a, WcatT, Wa);
    s_bin<<<S_BLOCKS + CHUNKS, 256, 0, stream>>>(h, Wa, edges, dense, rangeCnt,
                                                 sArrS, sArrD);
    gemm_scatter<<<NRANGE + GEMM_BLOCKS, 256, 0, stream>>>(
        h, WcatT, dense, rangeCnt, (const float4*)sArrS, (const float4*)sArrD,
        cnt, csr, hw8, scaleArr);

    msg_csr<<<(N_NODES + 3) / 4, 256, 0, stream>>>(cnt, csr, hw8, scaleArr, out);
}